// Round 9
// baseline (2778.930 us; speedup 1.0000x reference)
//
#include <hip/hip_runtime.h>
#include <cstddef>

#define MDIM 512
#define DDIM 1024
#define BDIM 4096
#define NLAYERS 16

constexpr int BK = 16;

__device__ __forceinline__ float softf(float v, float t) {
  // relu(v-t) - relu(-v-t) == copysign(max(|v|-t,0), v)
  return copysignf(fmaxf(fabsf(v) - t, 0.0f), v);
}

// ---------------------------------------------------------------------------
// C = P(rows x K, row-major) @ B(K x 4096, row-major), fused epilogue.
// Bit-exact accumulation: per output element one fmaf chain, k ascending
// (BK=16 chunks ascending, kk ascending within chunk) — identical chain to
// rounds 1/5/8 (absmax 0.2304688).
// Tile 16x128, 4 waves; wave = 4 rows x 128 cols, lane -> 2 cols.
//  - high occupancy: A-GEMM 1024 blocks (4/CU), B-GEMM 2048 blocks (8/CU)
//  - chunked XCD swizzle: consecutive logical blocks share a B-panel and
//    land on one XCD -> panel becomes L2-resident (m157/m204)
//  - A via wave-uniform LDS broadcast; B float2/lane (2-way, free);
//    Bs stride 132 -> even bank spread on staging writes
// MODE 0: layer-0 A-kernel; MODE 1: scan A-kernel; MODE 2: B-kernel (soft-Z)
// ---------------------------------------------------------------------------
template <int MODE, int K, int LOG2GX, int MINW>
__global__ __launch_bounds__(256, MINW) void gemm_ho(
    const float* __restrict__ P, const float* __restrict__ Bm,
    const float* __restrict__ xg, const float* __restrict__ Ep,
    const float* __restrict__ Lp, const float* __restrict__ Zp,
    const float* __restrict__ beta1, const float* __restrict__ beta2,
    const float* __restrict__ beta3, const float* __restrict__ ss2,
    const float* __restrict__ apar, const float* __restrict__ apar1, int k,
    float* __restrict__ O0, float* __restrict__ O1, float* __restrict__ O2) {
  __shared__ __align__(16) float As[2][BK][16];
  __shared__ __align__(16) float Bs[2][BK][132];  // pad: even bank spread

  const int tid = threadIdx.x;
  const int lane = tid & 63;
  const int w = __builtin_amdgcn_readfirstlane((int)(tid >> 6));

  // chunked XCD swizzle (bijective: nwg % 8 == 0)
  const int nwg = gridDim.x * gridDim.y;
  const int bid = blockIdx.x + gridDim.x * blockIdx.y;
  const int cpx = nwg >> 3;
  const int lgc = (bid & 7) * cpx + (bid >> 3);
  const int bx = lgc & ((1 << LOG2GX) - 1);
  const int by = lgc >> LOG2GX;

  const int m0 = bx * 16, n0 = by * 128;
  const int r0 = m0 + w * 4;     // wave's first row (wave-uniform)
  const int c0 = n0 + lane * 2;  // thread's 2 cols

  float acc[4][2];
#pragma unroll
  for (int r = 0; r < 4; ++r) {
    acc[r][0] = 0.0f;
    acc[r][1] = 0.0f;
  }

  // A staging: thread -> (row = tid>>4, kk = tid&15), 1 scalar load
  const int arow = tid >> 4, ak = tid & 15;
  const float* gA = P + (size_t)(m0 + arow) * K + ak;
  // B staging: thread -> (row = tid>>4, col-chunk = (tid&15)*8)
  const int brow = tid >> 4, bcol = (tid & 15) * 8;
  const float* gB = Bm + (size_t)brow * BDIM + n0 + bcol;

  float rA;
  float4 rB0, rB1;
  auto gload = [&](int k0) {
    rA = gA[(size_t)k0];
    rB0 = *reinterpret_cast<const float4*>(gB + (size_t)k0 * BDIM);
    rB1 = *reinterpret_cast<const float4*>(gB + (size_t)k0 * BDIM + 4);
  };
  auto stagewr = [&](int bb) {
    As[bb][ak][arow] = rA;
    *reinterpret_cast<float4*>(&Bs[bb][brow][bcol]) = rB0;
    *reinterpret_cast<float4*>(&Bs[bb][brow][bcol + 4]) = rB1;
  };
  auto comp = [&](int bb) {
#pragma unroll
    for (int kk = 0; kk < BK; ++kk) {
      // wave-uniform broadcast read of this wave's 4 A values
      const float4 a4 = *reinterpret_cast<const float4*>(&As[bb][kk][w * 4]);
      const float a[4] = {a4.x, a4.y, a4.z, a4.w};
      const float2 b2 = *reinterpret_cast<const float2*>(&Bs[bb][kk][lane * 2]);
#pragma unroll
      for (int r = 0; r < 4; ++r) {
        acc[r][0] = fmaf(a[r], b2.x, acc[r][0]);
        acc[r][1] = fmaf(a[r], b2.y, acc[r][1]);
      }
    }
  };

  constexpr int NS = K / BK;
  gload(0);
  stagewr(0);
  __syncthreads();
  int bb = 0;
#pragma unroll 1
  for (int t = 1; t < NS; ++t) {
    gload(t * BK);
    comp(bb);         // reads buffer bb
    stagewr(bb ^ 1);  // writes the other buffer — one barrier suffices
    __syncthreads();
    bb ^= 1;
  }
  comp(bb);

  // ---- epilogue (expressions identical to rounds 1/5/8) ----
  const float b1v = (MODE == 2) ? 0.f : beta1[k];
  float b2v = 0.f, b3v = 0.f, s2v = 0.f, a1v = 0.f, ap = 0.f;
  if (MODE == 1) {
    b2v = beta2[k - 1];
    b3v = beta3[k - 1];
    s2v = ss2[k - 1];
    a1v = apar1[k - 1];
  }
  if (MODE == 2) ap = apar[k];

#pragma unroll
  for (int r = 0; r < 4; ++r) {
    const size_t off = (size_t)(r0 + r) * BDIM + c0;
    if (MODE == 2) {
      const float2 z2 = *reinterpret_cast<const float2*>(&Zp[off]);
      float2 o;
      o.x = softf(z2.x - acc[r][0], ap);
      o.y = softf(z2.y - acc[r][1], ap);
      *reinterpret_cast<float2*>(&O0[off]) = o;
    } else {
      const float2 e2 = *reinterpret_cast<const float2*>(&Ep[off]);
      const float2 l2 = *reinterpret_cast<const float2*>(&Lp[off]);
      const float2 x2 = *reinterpret_cast<const float2*>(&xg[off]);
      const float ev[2] = {e2.x, e2.y};
      const float lv[2] = {l2.x, l2.y};
      const float xv[2] = {x2.x, x2.y};
      float vo[2], eo[2], lo_[2];
#pragma unroll
      for (int j = 0; j < 2; ++j) {
        const float az = acc[r][j];
        if (MODE == 0) {
          const float t0 = az + ev[j] - xv[j];
          vo[j] = fmaf(b1v, t0, lv[j]);
          eo[j] = ev[j];
          lo_[j] = lv[j];
        } else {
          const float vv = fmaf(b2v, az + ev[j] - xv[j], lv[j]);
          const float en = softf(ev[j] - s2v * vv, a1v);
          const float tn_ = az + en - xv[j];
          const float ln = fmaf(b3v, tn_, lv[j]);
          eo[j] = en;
          lo_[j] = ln;
          vo[j] = fmaf(b1v, tn_, ln);
        }
      }
      float2 t2;
      t2.x = vo[0];
      t2.y = vo[1];
      *reinterpret_cast<float2*>(&O0[off]) = t2;
      t2.x = eo[0];
      t2.y = eo[1];
      *reinterpret_cast<float2*>(&O1[off]) = t2;
      t2.x = lo_[0];
      t2.y = lo_[1];
      *reinterpret_cast<float2*>(&O2[off]) = t2;
    }
  }
}

extern "C" void kernel_launch(void* const* d_in, const int* in_sizes, int n_in,
                              void* d_out, int out_size, void* d_ws,
                              size_t ws_size, hipStream_t stream) {
  (void)in_sizes;
  (void)n_in;
  (void)out_size;
  (void)ws_size;
  const float* x = (const float*)d_in[0];
  const float* A = (const float*)d_in[1];
  const float* W = (const float*)d_in[2];
  const float* Z0 = (const float*)d_in[3];
  const float* E0 = (const float*)d_in[4];
  const float* L0 = (const float*)d_in[5];
  const float* beta1 = (const float*)d_in[6];
  const float* beta2 = (const float*)d_in[7];
  const float* beta3 = (const float*)d_in[8];
  const float* ss2 = (const float*)d_in[9];
  const float* apar = (const float*)d_in[10];
  const float* apar1 = (const float*)d_in[11];

  constexpr size_t DB = (size_t)DDIM * BDIM;
  constexpr size_t MB = (size_t)MDIM * BDIM;
  float* Zall = (float*)d_out;
  float* Eall = Zall + (size_t)NLAYERS * DB;
  float* Lall = Eall + (size_t)NLAYERS * MB;
  float* Var = (float*)d_ws;  // MDIM*BDIM floats = 8 MiB

  const dim3 blk(256);
  const dim3 gA(MDIM / 16, BDIM / 128);  // (32, 32) = 1024 blocks, 4/CU
  const dim3 gB(DDIM / 16, BDIM / 128);  // (64, 32) = 2048 blocks, 8/CU

  // layer 0
  gemm_ho<0, DDIM, 5, 4><<<gA, blk, 0, stream>>>(
      A, Z0, x, E0, L0, nullptr, beta1, beta2, beta3, ss2, apar, apar1, 0, Var,
      Eall, Lall);
  gemm_ho<2, MDIM, 6, 8><<<gB, blk, 0, stream>>>(
      W, Var, nullptr, nullptr, nullptr, Z0, beta1, beta2, beta3, ss2, apar,
      apar1, 0, Zall, nullptr, nullptr);
  // layers 1..15
  for (int k = 1; k < NLAYERS; ++k) {
    const float* Zp = Zall + (size_t)(k - 1) * DB;
    gemm_ho<1, DDIM, 5, 4><<<gA, blk, 0, stream>>>(
        A, Zp, x, Eall + (size_t)(k - 1) * MB, Lall + (size_t)(k - 1) * MB,
        nullptr, beta1, beta2, beta3, ss2, apar, apar1, k, Var,
        Eall + (size_t)k * MB, Lall + (size_t)k * MB);
    gemm_ho<2, MDIM, 6, 8><<<gB, blk, 0, stream>>>(
        W + (size_t)k * DDIM * MDIM, Var, nullptr, nullptr, nullptr, Zp, beta1,
        beta2, beta3, ss2, apar, apar1, k, Zall + (size_t)k * DB, nullptr,
        nullptr);
  }
}